// Round 1
// baseline (280.750 us; speedup 1.0000x reference)
//
#include <hip/hip_runtime.h>
#include <hip/hip_cooperative_groups.h>
#include <math.h>

namespace cg = cooperative_groups;

#define D_DIM   1024
#define BS      80      // B * STEP
#define STEPS   5
#define ALPHA   0.01f
#define BN_EPS  1e-5f
#define L2_EPS  1e-12f

#define K2_NN   10              // n's per wave in phase 2
#define GRID_BLOCKS 512         // 2048 waves; exactly 2 blocks/CU on 256 CUs

// ---------------------------------------------------------------------------
// One cooperative kernel, three phases separated by grid syncs.
//
// Phase 0 (all blocks): prefetch this wave's phase-2 W fragment (4 rows,
//   64 VGPRs) + bias into registers. Registers persist across grid.sync(),
//   so the 4 MB W read overlaps phase 1 and phase 2 starts with only q loads.
//
// Phase 1 (blocks 0..79): closed-form fast-weight readout
//   q[n,i] = ALPHA * sum_{s<=t} c_s x_k[s][i] prod_{r=s+1..t}(1-ALPHA x_k[r][i]^2)
//   t = n>>4, bb = n&15; keys x[bb*5+s], query v = x[n], c_s = dot(key_s, v).
//   Blocks 0..7 also zero the BN column-stat buffers.
//
// Phase 2 (all blocks): y = q @ W^T + b with fused BN column sums.
//   wave -> (jg = wave&255 -> 4 j's, ng = wave>>8 -> 10 n's). All loads
//   coalesced float4; butterfly reduce; lane 0 writes y + accumulates stats,
//   8 atomics per wave at the end.
//
// Phase 3 (blocks 0..79): BN (from colsum/colsumsq) + ReLU + row L2 norm.
// ---------------------------------------------------------------------------
__global__ __launch_bounds__(256, 2) void fused_all(
        const float* __restrict__ x,     const float* __restrict__ W,
        const float* __restrict__ bvec,  const float* __restrict__ gamma,
        const float* __restrict__ beta,  float* __restrict__ q,
        float* __restrict__ y,           float* __restrict__ colsum,
        float* __restrict__ colsumsq,    float* __restrict__ out)
{
    cg::grid_group grid = cg::this_grid();

    const int tid  = threadIdx.x;
    const int lane = tid & 63;
    const int wid  = tid >> 6;
    const int bid  = blockIdx.x;

    // ---------------- phase 0: prefetch phase-2 operands --------------------
    const int wave = bid * 4 + wid;      // 0..2047
    const int jg   = wave & 255;         // j-group: j0 = jg*4
    const int ng   = wave >> 8;          // 0..7
    const int j0   = jg * 4;
    const int n0   = ng * K2_NN;

    const float4* __restrict__ W4 = (const float4*)W;
    float4 w[4][4];
#pragma unroll
    for (int jj = 0; jj < 4; ++jj)
#pragma unroll
        for (int m = 0; m < 4; ++m)
            w[jj][m] = W4[(size_t)(j0 + jj) * 256 + lane + 64 * m];
    const float4 b4 = ((const float4*)bvec)[jg];

    // ---------------- phase 1: stats zero + q rows --------------------------
    if (bid < 4)       colsum  [bid * 256 + tid]       = 0.f;
    else if (bid < 8)  colsumsq[(bid - 4) * 256 + tid] = 0.f;

    __shared__ float sh[4][STEPS];

    if (bid < BS) {
        const int n  = bid;
        const int t  = n >> 4;
        const int bb = n & 15;

        const float4 v = ((const float4*)(x + (size_t)n * D_DIM))[tid];

        float4 k[STEPS];
#pragma unroll
        for (int s = 0; s < STEPS; ++s)
            k[s] = ((const float4*)(x + (size_t)(bb * STEPS + s) * D_DIM))[tid];

        float p[STEPS];
#pragma unroll
        for (int s = 0; s < STEPS; ++s)
            p[s] = k[s].x * v.x + k[s].y * v.y + k[s].z * v.z + k[s].w * v.w;

#pragma unroll
        for (int off = 32; off; off >>= 1) {
#pragma unroll
            for (int s = 0; s < STEPS; ++s) p[s] += __shfl_xor(p[s], off, 64);
        }

        if (lane == 0) {
#pragma unroll
            for (int s = 0; s < STEPS; ++s) sh[wid][s] = p[s];
        }
        __syncthreads();
        float c[STEPS];
#pragma unroll
        for (int s = 0; s < STEPS; ++s)
            c[s] = sh[0][s] + sh[1][s] + sh[2][s] + sh[3][s];

        float4 acc = make_float4(0.f, 0.f, 0.f, 0.f);
        for (int s = 0; s <= t; ++s) {
            const float4 xs = k[s];
            acc.x = acc.x * (1.f - ALPHA * xs.x * xs.x) + c[s] * xs.x;
            acc.y = acc.y * (1.f - ALPHA * xs.y * xs.y) + c[s] * xs.y;
            acc.z = acc.z * (1.f - ALPHA * xs.z * xs.z) + c[s] * xs.z;
            acc.w = acc.w * (1.f - ALPHA * xs.w * xs.w) + c[s] * xs.w;
        }
        acc.x *= ALPHA; acc.y *= ALPHA; acc.z *= ALPHA; acc.w *= ALPHA;
        ((float4*)(q + (size_t)n * D_DIM))[tid] = acc;
    }

    __threadfence();
    grid.sync();

    // ---------------- phase 2: GEMM + BN column stats -----------------------
    {
        const float4* __restrict__ q4 = (const float4*)q;

        float csum[4] = {0.f, 0.f, 0.f, 0.f};
        float csq [4] = {0.f, 0.f, 0.f, 0.f};

#pragma unroll 2
        for (int nn = 0; nn < K2_NN; ++nn) {
            const int n = n0 + nn;
            float4 qv[4];
#pragma unroll
            for (int m = 0; m < 4; ++m)
                qv[m] = q4[(size_t)n * 256 + lane + 64 * m];

            float s[4] = {0.f, 0.f, 0.f, 0.f};
#pragma unroll
            for (int jj = 0; jj < 4; ++jj) {
#pragma unroll
                for (int m = 0; m < 4; ++m) {
                    s[jj] += w[jj][m].x * qv[m].x + w[jj][m].y * qv[m].y
                           + w[jj][m].z * qv[m].z + w[jj][m].w * qv[m].w;
                }
            }
#pragma unroll
            for (int off = 32; off; off >>= 1) {
#pragma unroll
                for (int jj = 0; jj < 4; ++jj) s[jj] += __shfl_xor(s[jj], off, 64);
            }
            if (lane == 0) {
                float4 yv = make_float4(s[0] + b4.x, s[1] + b4.y,
                                        s[2] + b4.z, s[3] + b4.w);
                ((float4*)y)[(size_t)n * 256 + jg] = yv;
                csum[0] += yv.x; csum[1] += yv.y; csum[2] += yv.z; csum[3] += yv.w;
                csq[0] += yv.x * yv.x; csq[1] += yv.y * yv.y;
                csq[2] += yv.z * yv.z; csq[3] += yv.w * yv.w;
            }
        }
        if (lane == 0) {
#pragma unroll
            for (int jj = 0; jj < 4; ++jj) {
                atomicAdd(&colsum [j0 + jj], csum[jj]);
                atomicAdd(&colsumsq[j0 + jj], csq[jj]);
            }
        }
    }

    __threadfence();
    grid.sync();

    // ---------------- phase 3: BN + ReLU + row L2 normalize -----------------
    if (bid < BS) {
        const int n = bid;
        const float inv_bs = 1.f / (float)BS;

        float o[4];
        float ss = 0.f;
#pragma unroll
        for (int m = 0; m < 4; ++m) {
            const int j = tid + 256 * m;
            const float mu   = colsum[j] * inv_bs;
            const float var  = colsumsq[j] * inv_bs - mu * mu;
            const float istd = rsqrtf(var + BN_EPS);
            float v = (y[(size_t)n * D_DIM + j] - mu) * istd * gamma[j] + beta[j];
            v = fmaxf(v, 0.f);
            o[m] = v;
            ss += v * v;
        }

#pragma unroll
        for (int off = 32; off; off >>= 1) ss += __shfl_xor(ss, off, 64);
        __shared__ float sred[4];
        if ((tid & 63) == 0) sred[tid >> 6] = ss;
        __syncthreads();
        const float stot = sred[0] + sred[1] + sred[2] + sred[3];

        const float scale = 1.f / fmaxf(sqrtf(stot), L2_EPS);
#pragma unroll
        for (int m = 0; m < 4; ++m)
            out[(size_t)n * D_DIM + tid + 256 * m] = o[m] * scale;
    }
}

extern "C" void kernel_launch(void* const* d_in, const int* in_sizes, int n_in,
                              void* d_out, int out_size, void* d_ws, size_t ws_size,
                              hipStream_t stream) {
    const float* x     = (const float*)d_in[0];
    const float* W     = (const float*)d_in[1];
    const float* bvec  = (const float*)d_in[2];
    const float* gamma = (const float*)d_in[3];
    const float* beta  = (const float*)d_in[4];

    float* q        = (float*)d_ws;            // 80*1024
    float* y        = q + BS * D_DIM;          // 80*1024
    float* colsum   = y + BS * D_DIM;          // 1024
    float* colsumsq = colsum + D_DIM;          // 1024

    float* out = (float*)d_out;

    void* args[] = {(void*)&x, (void*)&W, (void*)&bvec, (void*)&gamma,
                    (void*)&beta, (void*)&q, (void*)&y, (void*)&colsum,
                    (void*)&colsumsq, (void*)&out};
    hipLaunchCooperativeKernel((const void*)fused_all, dim3(GRID_BLOCKS),
                               dim3(256), args, 0, stream);
}

// Round 2
// 81.273 us; speedup vs baseline: 3.4544x; 3.4544x over previous
//
#include <hip/hip_runtime.h>
#include <math.h>

#define D_DIM   1024
#define BS      80      // B * STEP
#define STEPS   5
#define ALPHA   0.01f
#define BN_EPS  1e-5f
#define L2_EPS  1e-12f

#define K2_NN   10      // rows per n-group
#define NG      8       // n-groups (NG * K2_NN == BS)
#define A_BLOCKS 512    // 64 blocks per n-group; exactly 2 blocks/CU

// ---------------------------------------------------------------------------
// Kernel A: per-block fused fast-weight readout + GEMM + partial BN stats.
//
//  Mapping: wave = bid*4+wid in [0,2048); jg = wave&255 (4 j's: j0=jg*4);
//           ng = bid>>6 in [0,8) (all 4 waves of a block share ng);
//           block covers 16 j-columns x 10 n-rows.
//
//  Phase 0: prefetch W fragment (4 rows x 4 KiB, 64 VGPRs) + bias. These
//           loads are in flight during phase 1 (latency hidden).
//  Phase 1: block computes its 10 q rows into LDS. Each wave handles rows
//           r = wid, wid+4, ... autonomously: loads the full row (16 elems
//           /lane), 5 dot-products via butterfly shfl, closed-form
//           recurrence, float4 store to LDS. One __syncthreads() total.
//             q[n,i] = ALPHA * sum_{s<=t} c_s x_k[s][i]
//                      * prod_{r=s+1..t}(1 - ALPHA x_k[r][i]^2),
//             t = n>>4, bb = n&15, keys x[bb*5+s], c_s = dot(key_s, x[n]).
//  Phase 2: y[n, j0..j0+3] = q[n] . W[j]^T + b[j] for the 10 n's; q from
//           LDS, W from registers; butterfly reduce; lane 0 writes y and
//           accumulates column partial sums; one partial-vector store per
//           wave at the end (psum/psq[ng][j]) -- no atomics anywhere.
// ---------------------------------------------------------------------------
__global__ __launch_bounds__(256, 2) void kA(const float* __restrict__ x,
                                             const float* __restrict__ W,
                                             const float* __restrict__ bvec,
                                             float* __restrict__ y,
                                             float* __restrict__ psum,
                                             float* __restrict__ psq) {
    const int tid  = threadIdx.x;
    const int lane = tid & 63;
    const int wid  = tid >> 6;
    const int bid  = blockIdx.x;
    const int wave = bid * 4 + wid;
    const int jg   = wave & 255;
    const int j0   = jg * 4;
    const int ng   = bid >> 6;          // 64 blocks per ng
    const int n0   = ng * K2_NN;

    __shared__ float qs[K2_NN][D_DIM];  // 40 KiB

    const float4* __restrict__ x4 = (const float4*)x;
    const float4* __restrict__ W4 = (const float4*)W;

    // ---- phase 0: W fragment + bias prefetch --------------------------------
    float4 w[4][4];
#pragma unroll
    for (int jj = 0; jj < 4; ++jj)
#pragma unroll
        for (int m = 0; m < 4; ++m)
            w[jj][m] = W4[(size_t)(j0 + jj) * 256 + lane + 64 * m];
    const float4 b4 = ((const float4*)bvec)[jg];

    // ---- phase 1: q rows into LDS ------------------------------------------
    for (int r = wid; r < K2_NN; r += 4) {
        const int n  = n0 + r;
        const int t  = n >> 4;          // wave-uniform
        const int bb = n & 15;

        float4 v[4];
#pragma unroll
        for (int m = 0; m < 4; ++m)
            v[m] = x4[(size_t)n * 256 + lane + 64 * m];

        float4 k[STEPS][4];
        float p[STEPS];
#pragma unroll
        for (int s = 0; s < STEPS; ++s) {
            if (s <= t) {               // uniform branch: skip unused keys
#pragma unroll
                for (int m = 0; m < 4; ++m)
                    k[s][m] = x4[(size_t)(bb * STEPS + s) * 256 + lane + 64 * m];
                float d = 0.f;
#pragma unroll
                for (int m = 0; m < 4; ++m)
                    d += k[s][m].x * v[m].x + k[s][m].y * v[m].y
                       + k[s][m].z * v[m].z + k[s][m].w * v[m].w;
                p[s] = d;
            } else {
                p[s] = 0.f;
            }
        }
#pragma unroll
        for (int off = 32; off; off >>= 1) {
#pragma unroll
            for (int s = 0; s < STEPS; ++s) p[s] += __shfl_xor(p[s], off, 64);
        }

        float4 acc[4];
#pragma unroll
        for (int m = 0; m < 4; ++m) acc[m] = make_float4(0.f, 0.f, 0.f, 0.f);
#pragma unroll
        for (int s = 0; s < STEPS; ++s) {   // static indexing (no scratch)
            if (s <= t) {
#pragma unroll
                for (int m = 0; m < 4; ++m) {
                    acc[m].x = acc[m].x * (1.f - ALPHA * k[s][m].x * k[s][m].x) + p[s] * k[s][m].x;
                    acc[m].y = acc[m].y * (1.f - ALPHA * k[s][m].y * k[s][m].y) + p[s] * k[s][m].y;
                    acc[m].z = acc[m].z * (1.f - ALPHA * k[s][m].z * k[s][m].z) + p[s] * k[s][m].z;
                    acc[m].w = acc[m].w * (1.f - ALPHA * k[s][m].w * k[s][m].w) + p[s] * k[s][m].w;
                }
            }
        }
#pragma unroll
        for (int m = 0; m < 4; ++m) {
            acc[m].x *= ALPHA; acc[m].y *= ALPHA; acc[m].z *= ALPHA; acc[m].w *= ALPHA;
            ((float4*)qs[r])[lane + 64 * m] = acc[m];
        }
    }
    __syncthreads();

    // ---- phase 2: GEMM + partial column stats ------------------------------
    float csum[4] = {0.f, 0.f, 0.f, 0.f};
    float csq [4] = {0.f, 0.f, 0.f, 0.f};

#pragma unroll 2
    for (int nn = 0; nn < K2_NN; ++nn) {
        const int n = n0 + nn;
        float4 qv[4];
#pragma unroll
        for (int m = 0; m < 4; ++m)
            qv[m] = ((const float4*)qs[nn])[lane + 64 * m];

        float s[4] = {0.f, 0.f, 0.f, 0.f};
#pragma unroll
        for (int jj = 0; jj < 4; ++jj) {
#pragma unroll
            for (int m = 0; m < 4; ++m) {
                s[jj] += w[jj][m].x * qv[m].x + w[jj][m].y * qv[m].y
                       + w[jj][m].z * qv[m].z + w[jj][m].w * qv[m].w;
            }
        }
#pragma unroll
        for (int off = 32; off; off >>= 1) {
#pragma unroll
            for (int jj = 0; jj < 4; ++jj) s[jj] += __shfl_xor(s[jj], off, 64);
        }
        if (lane == 0) {
            float4 yv = make_float4(s[0] + b4.x, s[1] + b4.y,
                                    s[2] + b4.z, s[3] + b4.w);
            ((float4*)y)[(size_t)n * 256 + jg] = yv;
            csum[0] += yv.x; csum[1] += yv.y; csum[2] += yv.z; csum[3] += yv.w;
            csq[0] += yv.x * yv.x; csq[1] += yv.y * yv.y;
            csq[2] += yv.z * yv.z; csq[3] += yv.w * yv.w;
        }
    }
    if (lane == 0) {
        ((float4*)psum)[ng * 256 + jg] = make_float4(csum[0], csum[1], csum[2], csum[3]);
        ((float4*)psq )[ng * 256 + jg] = make_float4(csq [0], csq [1], csq [2], csq [3]);
    }
}

// ---------------------------------------------------------------------------
// Kernel B: reduce the NG=8 partials per column -> BN stats, then
// BN + ReLU + row L2-normalize. One block per row; each thread owns one
// float4 (4 consecutive j) -- everything float4, fully coalesced.
// ---------------------------------------------------------------------------
__global__ __launch_bounds__(256) void kB(const float* __restrict__ y,
                                          const float* __restrict__ psum,
                                          const float* __restrict__ psq,
                                          const float* __restrict__ gamma,
                                          const float* __restrict__ beta,
                                          float* __restrict__ out) {
    const int n   = blockIdx.x;
    const int tid = threadIdx.x;

    float4 su = make_float4(0.f, 0.f, 0.f, 0.f);
    float4 sq = make_float4(0.f, 0.f, 0.f, 0.f);
#pragma unroll
    for (int g = 0; g < NG; ++g) {
        const float4 a = ((const float4*)psum)[g * 256 + tid];
        const float4 b = ((const float4*)psq )[g * 256 + tid];
        su.x += a.x; su.y += a.y; su.z += a.z; su.w += a.w;
        sq.x += b.x; sq.y += b.y; sq.z += b.z; sq.w += b.w;
    }
    const float inv_bs = 1.f / (float)BS;
    const float4 yv = ((const float4*)y)[(size_t)n * 256 + tid];
    const float4 g4 = ((const float4*)gamma)[tid];
    const float4 be = ((const float4*)beta)[tid];

    float4 o;
    {
        const float mu = su.x * inv_bs;
        const float istd = rsqrtf(sq.x * inv_bs - mu * mu + BN_EPS);
        o.x = fmaxf((yv.x - mu) * istd * g4.x + be.x, 0.f);
    }
    {
        const float mu = su.y * inv_bs;
        const float istd = rsqrtf(sq.y * inv_bs - mu * mu + BN_EPS);
        o.y = fmaxf((yv.y - mu) * istd * g4.y + be.y, 0.f);
    }
    {
        const float mu = su.z * inv_bs;
        const float istd = rsqrtf(sq.z * inv_bs - mu * mu + BN_EPS);
        o.z = fmaxf((yv.z - mu) * istd * g4.z + be.z, 0.f);
    }
    {
        const float mu = su.w * inv_bs;
        const float istd = rsqrtf(sq.w * inv_bs - mu * mu + BN_EPS);
        o.w = fmaxf((yv.w - mu) * istd * g4.w + be.w, 0.f);
    }

    float ss = o.x * o.x + o.y * o.y + o.z * o.z + o.w * o.w;
#pragma unroll
    for (int off = 32; off; off >>= 1) ss += __shfl_xor(ss, off, 64);
    __shared__ float sred[4];
    if ((tid & 63) == 0) sred[tid >> 6] = ss;
    __syncthreads();
    const float stot = sred[0] + sred[1] + sred[2] + sred[3];

    const float scale = 1.f / fmaxf(sqrtf(stot), L2_EPS);
    float4 ov = make_float4(o.x * scale, o.y * scale, o.z * scale, o.w * scale);
    ((float4*)out)[(size_t)n * 256 + tid] = ov;
}

extern "C" void kernel_launch(void* const* d_in, const int* in_sizes, int n_in,
                              void* d_out, int out_size, void* d_ws, size_t ws_size,
                              hipStream_t stream) {
    const float* x     = (const float*)d_in[0];
    const float* W     = (const float*)d_in[1];
    const float* bvec  = (const float*)d_in[2];
    const float* gamma = (const float*)d_in[3];
    const float* beta  = (const float*)d_in[4];

    float* y    = (float*)d_ws;          // 80*1024
    float* psum = y + BS * D_DIM;        // 8*1024
    float* psq  = psum + NG * D_DIM;     // 8*1024

    float* out = (float*)d_out;

    kA<<<A_BLOCKS, 256, 0, stream>>>(x, W, bvec, y, psum, psq);
    kB<<<BS,       256, 0, stream>>>(y, psum, psq, gamma, beta, out);
}

// Round 4
// 78.913 us; speedup vs baseline: 3.5577x; 1.0299x over previous
//
#include <hip/hip_runtime.h>
#include <math.h>

#define D_DIM   1024
#define BS      80      // B * STEP
#define STEPS   5
#define ALPHA   0.01f
#define BN_EPS  1e-5f
#define L2_EPS  1e-12f

#define NG      8       // n-groups
#define NROWS   10      // rows per n-group (NG*NROWS == BS)
#define JBLK    128     // j-blocks of 8 columns each
#define G_BLOCKS (NG * JBLK)   // 1024 blocks; 4 blocks/CU

// ---------------------------------------------------------------------------
// kQ: closed-form fast-weight readout, one block per row (computed ONCE).
//   q[n,i] = ALPHA * sum_{s<=t} c_s x_k[s][i] prod_{r=s+1..t}(1-ALPHA x_k[r][i]^2)
//   t = n>>4, bb = n&15; keys x[bb*5+s], query v = x[n], c_s = dot(key_s, v).
// 256 threads x float4 = exact row fit.
// ---------------------------------------------------------------------------
__global__ __launch_bounds__(256) void kQ(const float* __restrict__ x,
                                          float* __restrict__ q) {
    const int n    = blockIdx.x;
    const int tid  = threadIdx.x;
    const int lane = tid & 63;
    const int wid  = tid >> 6;
    const int t    = n >> 4;
    const int bb   = n & 15;

    const float4* __restrict__ xv = (const float4*)(x + (size_t)n * D_DIM);
    const float4 v = xv[tid];

    float4 k[STEPS];
#pragma unroll
    for (int s = 0; s < STEPS; ++s)
        k[s] = ((const float4*)(x + (size_t)(bb * STEPS + s) * D_DIM))[tid];

    float p[STEPS];
#pragma unroll
    for (int s = 0; s < STEPS; ++s)
        p[s] = k[s].x * v.x + k[s].y * v.y + k[s].z * v.z + k[s].w * v.w;

#pragma unroll
    for (int off = 32; off; off >>= 1) {
#pragma unroll
        for (int s = 0; s < STEPS; ++s) p[s] += __shfl_xor(p[s], off, 64);
    }

    __shared__ float sh[4][STEPS];
    if (lane == 0) {
#pragma unroll
        for (int s = 0; s < STEPS; ++s) sh[wid][s] = p[s];
    }
    __syncthreads();
    float c[STEPS];
#pragma unroll
    for (int s = 0; s < STEPS; ++s)
        c[s] = sh[0][s] + sh[1][s] + sh[2][s] + sh[3][s];

    float4 acc = make_float4(0.f, 0.f, 0.f, 0.f);
    for (int s = 0; s <= t; ++s) {
        const float4 xs = k[s];
        acc.x = acc.x * (1.f - ALPHA * xs.x * xs.x) + c[s] * xs.x;
        acc.y = acc.y * (1.f - ALPHA * xs.y * xs.y) + c[s] * xs.y;
        acc.z = acc.z * (1.f - ALPHA * xs.z * xs.z) + c[s] * xs.z;
        acc.w = acc.w * (1.f - ALPHA * xs.w * xs.w) + c[s] * xs.w;
    }
    acc.x *= ALPHA; acc.y *= ALPHA; acc.z *= ALPHA; acc.w *= ALPHA;
    ((float4*)(q + (size_t)n * D_DIM))[tid] = acc;
}

// ---------------------------------------------------------------------------
// kG: y = q @ W^T + b with per-(ng, j) partial BN stats. 1024 blocks.
//   bid = ng*128 + jb. XCD swizzle property: the 8 blocks sharing jb (same
//   8 W rows) have bid ≡ jb (mod 8) -> same XCD under round-robin dispatch
//   -> W row fetched from HBM once, 7 L2 hits (caches are cold each
//   iteration: the harness's 256 MiB poison evicts L2+L3).
//   Per block: 8 j-columns x 10 n-rows. Wave wid owns j = j0+2*wid, +1
//   (2 W rows = 32 VGPRs). q n-tile staged once into 40 KiB LDS (coalesced).
//   4 blocks/CU (LDS 160/40), VGPR<=128 via __launch_bounds__(256,4)
//   -> 16 waves/CU, 2x round-2 occupancy.
//   Stats: each (ng, j) partial owned by exactly one wave -> no atomics.
// ---------------------------------------------------------------------------
__global__ __launch_bounds__(256, 4) void kG(const float* __restrict__ q,
                                             const float* __restrict__ W,
                                             const float* __restrict__ bvec,
                                             float* __restrict__ y,
                                             float* __restrict__ psum,
                                             float* __restrict__ psq) {
    const int tid  = threadIdx.x;
    const int lane = tid & 63;
    const int wid  = tid >> 6;
    const int bid  = blockIdx.x;
    const int ng   = bid >> 7;         // 0..7
    const int jb   = bid & 127;        // 0..127
    const int j0   = jb * 8;
    const int n0   = ng * NROWS;
    const int jw   = j0 + wid * 2;     // this wave's 2 columns

    __shared__ float qs[NROWS][D_DIM];  // 40 KiB

    // W fragment prefetch (in flight during q staging)
    const float4* __restrict__ W4 = (const float4*)W;
    float4 w[2][4];
#pragma unroll
    for (int jj = 0; jj < 2; ++jj)
#pragma unroll
        for (int m = 0; m < 4; ++m)
            w[jj][m] = W4[(size_t)(jw + jj) * 256 + lane + 64 * m];
    const float b0 = bvec[jw];
    const float b1 = bvec[jw + 1];

    // stage this n-group's q rows into LDS, fully coalesced
    {
        const float4* __restrict__ q4 = (const float4*)(q + (size_t)n0 * D_DIM);
        float4* __restrict__ qs4 = (float4*)qs;
#pragma unroll
        for (int i = 0; i < (NROWS * 256) / 256; ++i)
            qs4[tid + 256 * i] = q4[tid + 256 * i];
    }
    __syncthreads();

    float csum[2] = {0.f, 0.f};
    float csq [2] = {0.f, 0.f};

#pragma unroll 2
    for (int nn = 0; nn < NROWS; ++nn) {
        const int n = n0 + nn;
        float4 qv[4];
#pragma unroll
        for (int m = 0; m < 4; ++m)
            qv[m] = ((const float4*)qs[nn])[lane + 64 * m];

        float s0 = 0.f, s1 = 0.f;
#pragma unroll
        for (int m = 0; m < 4; ++m) {
            s0 += w[0][m].x * qv[m].x + w[0][m].y * qv[m].y
                + w[0][m].z * qv[m].z + w[0][m].w * qv[m].w;
            s1 += w[1][m].x * qv[m].x + w[1][m].y * qv[m].y
                + w[1][m].z * qv[m].z + w[1][m].w * qv[m].w;
        }
#pragma unroll
        for (int off = 32; off; off >>= 1) {
            s0 += __shfl_xor(s0, off, 64);
            s1 += __shfl_xor(s1, off, 64);
        }
        if (lane == 0) {
            const float y0 = s0 + b0;
            const float y1 = s1 + b1;
            ((float2*)(y + (size_t)n * D_DIM + jw))[0] = make_float2(y0, y1);
            csum[0] += y0; csum[1] += y1;
            csq [0] += y0 * y0; csq [1] += y1 * y1;
        }
    }
    if (lane == 0) {
        ((float2*)(psum + (size_t)ng * D_DIM + jw))[0] = make_float2(csum[0], csum[1]);
        ((float2*)(psq  + (size_t)ng * D_DIM + jw))[0] = make_float2(csq [0], csq [1]);
    }
}

// ---------------------------------------------------------------------------
// kB: reduce NG=8 partials per column -> BN stats; BN + ReLU + row L2 norm.
// One block per row; one float4 per thread.
// ---------------------------------------------------------------------------
__global__ __launch_bounds__(256) void kB(const float* __restrict__ y,
                                          const float* __restrict__ psum,
                                          const float* __restrict__ psq,
                                          const float* __restrict__ gamma,
                                          const float* __restrict__ beta,
                                          float* __restrict__ out) {
    const int n   = blockIdx.x;
    const int tid = threadIdx.x;

    float4 su = make_float4(0.f, 0.f, 0.f, 0.f);
    float4 sq = make_float4(0.f, 0.f, 0.f, 0.f);
#pragma unroll
    for (int g = 0; g < NG; ++g) {
        const float4 a = ((const float4*)psum)[g * 256 + tid];
        const float4 b = ((const float4*)psq )[g * 256 + tid];
        su.x += a.x; su.y += a.y; su.z += a.z; su.w += a.w;
        sq.x += b.x; sq.y += b.y; sq.z += b.z; sq.w += b.w;
    }
    const float inv_bs = 1.f / (float)BS;
    const float4 yv = ((const float4*)y)[(size_t)n * 256 + tid];
    const float4 g4 = ((const float4*)gamma)[tid];
    const float4 be = ((const float4*)beta)[tid];

    float4 o;
    {
        const float mu = su.x * inv_bs;
        const float istd = rsqrtf(sq.x * inv_bs - mu * mu + BN_EPS);
        o.x = fmaxf((yv.x - mu) * istd * g4.x + be.x, 0.f);
    }
    {
        const float mu = su.y * inv_bs;
        const float istd = rsqrtf(sq.y * inv_bs - mu * mu + BN_EPS);
        o.y = fmaxf((yv.y - mu) * istd * g4.y + be.y, 0.f);
    }
    {
        const float mu = su.z * inv_bs;
        const float istd = rsqrtf(sq.z * inv_bs - mu * mu + BN_EPS);
        o.z = fmaxf((yv.z - mu) * istd * g4.z + be.z, 0.f);
    }
    {
        const float mu = su.w * inv_bs;
        const float istd = rsqrtf(sq.w * inv_bs - mu * mu + BN_EPS);
        o.w = fmaxf((yv.w - mu) * istd * g4.w + be.w, 0.f);
    }

    float ss = o.x * o.x + o.y * o.y + o.z * o.z + o.w * o.w;
#pragma unroll
    for (int off = 32; off; off >>= 1) ss += __shfl_xor(ss, off, 64);
    __shared__ float sred[4];
    if ((tid & 63) == 0) sred[tid >> 6] = ss;
    __syncthreads();
    const float stot = sred[0] + sred[1] + sred[2] + sred[3];

    const float scale = 1.f / fmaxf(sqrtf(stot), L2_EPS);
    float4 ov = make_float4(o.x * scale, o.y * scale, o.z * scale, o.w * scale);
    ((float4*)out)[(size_t)n * 256 + tid] = ov;
}

extern "C" void kernel_launch(void* const* d_in, const int* in_sizes, int n_in,
                              void* d_out, int out_size, void* d_ws, size_t ws_size,
                              hipStream_t stream) {
    const float* x     = (const float*)d_in[0];
    const float* W     = (const float*)d_in[1];
    const float* bvec  = (const float*)d_in[2];
    const float* gamma = (const float*)d_in[3];
    const float* beta  = (const float*)d_in[4];

    float* q    = (float*)d_ws;          // 80*1024
    float* y    = q + BS * D_DIM;        // 80*1024
    float* psum = y + BS * D_DIM;        // 8*1024
    float* psq  = psum + NG * D_DIM;     // 8*1024

    float* out = (float*)d_out;

    kQ<<<BS,       256, 0, stream>>>(x, q);
    kG<<<G_BLOCKS, 256, 0, stream>>>(q, W, bvec, y, psum, psq);
    kB<<<BS,       256, 0, stream>>>(y, psum, psq, gamma, beta, out);
}